// Round 12
// baseline (182.825 us; speedup 1.0000x reference)
//
#include <hip/hip_runtime.h>
#include <cstdint>
#include <cstddef>

// MultiHeadSelfAttention: B=2, S=2048, D=1024, H=16, Hd=64
// Pipeline (4 dispatches):
//   0.  convert_fused: xb = bf16(x) AND wT = bf16(transpose(w))
//   1.  fused QKV GEMM, 128x128, grid (8,32,3).
//         R11: launch_bounds back to (256,2) (R10's (256,3) regressed QKV
//         43->52us: occupancy stayed ~2 blocks/CU -- 3x51.2KB LDS doesn't fit
//         after rounding -- while codegen got worse, VGPR 48->68).
//         R11: V-epilogue t_s shrunk [128][136]->[128][72] via TWO-PASS
//         (m-halves) transpose: QKV LDS 51.2->34.8KB so 4 blocks/CU fit
//         naturally (VGPR 48; launch_bounds only sets the floor).
//         Q -> bf16 [B*H, S, 64], PRE-SCALED by 0.125*log2(e)
//         K -> bf16 [B*H, S, 64], XOR-16B-granule swizzle (granule ^= seq&7)
//         V -> bf16 [B*H, chunk, d, key] chunked+permuted+swizzled
//   2.  flash attention (R9 config, unchanged -- control at ~43.3us):
//         8 waves = 4 q-waves x 64q x 2 key-halves, tile 256q, grid (8,32).
//         Offset-free streaming softmax (p=2^{s'}, scores O(+-5)).
//   3.  O-proj GEMM -> fp32 d_out (R10 config, kept: 128x64, grid (16,32),
//         (256,4) -- inferred ~9us gain in R10).
//
// History: R0 4wx32q occup 18%; R1 8wx16q LDS-pipe 2x; R2 kh-split 48.4;
// R3 reg-batch spilled @cap128; R4 setprio null; R6 cvtpk -4us; R7 T1 swizzle
// (attn FETCH 71->14MB); R8 small-tile QKV regressed; R9 64q/wave attn 43.3;
// R10 QKV (256,3) regressed +9us / O-proj 128x64@4 gained ~9us.

typedef float floatx4 __attribute__((ext_vector_type(4)));
typedef __bf16 bf16x8 __attribute__((ext_vector_type(8)));
union ABFrag { bf16x8 v; uint4 q; unsigned short u[8]; unsigned int w[4]; };

__device__ __forceinline__ unsigned short f2bf(float f) {
    unsigned int u = __builtin_bit_cast(unsigned int, f);
    return (unsigned short)((u + 0x7FFFu + ((u >> 16) & 1u)) >> 16);  // RNE
}

// pack two floats to bf16x2 in ONE VALU op (RNE)
__device__ __forceinline__ unsigned int cvtpk(float lo, float hi) {
    unsigned int r;
    asm("v_cvt_pk_bf16_f32 %0, %1, %2" : "=v"(r) : "v"(lo), "v"(hi));
    return r;
}

#if __has_builtin(__builtin_amdgcn_exp2f)
#define EXP2F(x) __builtin_amdgcn_exp2f(x)
#else
#define EXP2F(x) exp2f(x)
#endif

// async global->LDS, 16B/lane; LDS dst = wave-uniform base + lane*16
__device__ __forceinline__ void glds16(const void* g, void* l) {
    __builtin_amdgcn_global_load_lds(
        (const __attribute__((address_space(1))) unsigned int*)(uintptr_t)g,
        (__attribute__((address_space(3))) unsigned int*)(unsigned int)(uintptr_t)l,
        16, 0, 0);
}

// ---------------------------------------------------------------------------
// Fused convert. Blocks [0,2048): x -> bf16. Blocks [2048,6144): w -> wT.
// ---------------------------------------------------------------------------
__global__ void convert_fused_kernel(const float* __restrict__ x,
                                     const float* __restrict__ w0,
                                     const float* __restrict__ w1,
                                     const float* __restrict__ w2,
                                     const float* __restrict__ w3,
                                     unsigned short* __restrict__ xb,
                                     unsigned short* __restrict__ wT) {
    const int tid = threadIdx.x;
    if (blockIdx.x < 2048) {
        int i = (blockIdx.x * 256 + tid) * 8;
        float4 a = *(const float4*)(x + i);
        float4 b = *(const float4*)(x + i + 4);
        union { unsigned short u[8]; uint4 q; } o;
        o.u[0] = f2bf(a.x); o.u[1] = f2bf(a.y); o.u[2] = f2bf(a.z); o.u[3] = f2bf(a.w);
        o.u[4] = f2bf(b.x); o.u[5] = f2bf(b.y); o.u[6] = f2bf(b.z); o.u[7] = f2bf(b.w);
        *(uint4*)(xb + i) = o.q;
        return;
    }
    __shared__ unsigned short t[32][40];
    const int wi = blockIdx.x - 2048;          // [0,4096)
    const int z  = wi >> 10;                   // weight matrix 0..3
    const int rem = wi & 1023;
    const int k0 = (rem >> 5) * 32, n0 = (rem & 31) * 32;
    const float* w = (z == 0) ? w0 : (z == 1) ? w1 : (z == 2) ? w2 : w3;
    unsigned short* dst = wT + (size_t)z * 1024 * 1024;
    {
        int ry = tid >> 3, cx = (tid & 7) * 4;
        float4 v = *(const float4*)(w + (size_t)(k0 + ry) * 1024 + n0 + cx);
        t[cx + 0][ry] = f2bf(v.x); t[cx + 1][ry] = f2bf(v.y);
        t[cx + 2][ry] = f2bf(v.z); t[cx + 3][ry] = f2bf(v.w);
    }
    __syncthreads();
    int n = tid >> 3, kc = (tid & 7) * 4;
    *(uint2*)(dst + (size_t)(n0 + n) * 1024 + k0 + kc) = *(const uint2*)&t[n][kc];
}

// ---------------------------------------------------------------------------
// m97-style GEMM. KIND 0: fused QKV, 128x128, grid (8,32,3), LDS 34.8KB
//   (4 blocks/CU via LDS shrink; launch_bounds (256,2) = R9 codegen).
// KIND 1: O-proj, fp32 out, 128x64, grid (16,32), (256,4).
// XCD swizzle: work id = (hwlin&7)*cpx + hwlin>>3 (bijective, nwg%8==0).
// ---------------------------------------------------------------------------
template<int KIND>
__launch_bounds__(256, (KIND == 0) ? 2 : 4)
__global__ void gemm_kernel(const unsigned short* __restrict__ A,
                            const unsigned short* __restrict__ wT,
                            const float* __restrict__ bias0,
                            const float* __restrict__ bias1,
                            const float* __restrict__ bias2,
                            void* __restrict__ out0,
                            void* __restrict__ out1,
                            void* __restrict__ out2)
{
    constexpr int BM = 128;
    constexpr int BN = (KIND == 1) ? 64 : 128;
    constexpr int NI = BM / 32;                  // 4
    constexpr int NJ = BN / 32;                  // 2 or 4

    __shared__ unsigned short a_s[BM * 32];
    __shared__ unsigned short b_s[BN * 32];

    // ---- T1 XCD swizzle ----
    int bx, by, bz;
    if constexpr (KIND == 0) {
        // grid (8,32,3), nwg=768, cpx=96; layout x + 8y + 256z (z-major/XCD)
        int lin = blockIdx.x + (blockIdx.y << 3) + (blockIdx.z << 8);
        int swz = (lin & 7) * 96 + (lin >> 3);
        bx = swz & 7;
        int rem = swz >> 3;            // y + 32z, [0,96)
        by = rem & 31;
        bz = rem >> 5;
    } else {
        // grid (16,32), nwg=512, cpx=64
        int lin = blockIdx.x + (blockIdx.y << 4);
        int swz = ((lin & 7) << 6) + (lin >> 3);
        bx = swz & 15;
        by = swz >> 4;
        bz = 0;
    }

    const int tid  = threadIdx.x;
    const int wid  = tid >> 6;
    const int lane = tid & 63;
    const int quad = lane >> 4;
    const int l15  = lane & 15;
    const int wm   = (wid >> 1) * (BM / 2);
    const int wn   = (wid & 1) * (BN / 2);
    const int m0   = by * BM;
    const int n0   = bx * BN;

    const unsigned short* Bt = (KIND == 0) ? wT + (size_t)bz * (1024 * 1024) : wT;
    const float* bias = (KIND == 0)
        ? (bz == 0 ? bias0 : bz == 1 ? bias1 : bias2) : bias0;

    const int sr = lane >> 2;
    const int sc = (lane & 3) * 8;
    // staging rows/wave: A = 32 (2 glds), B = BN/4 (KIND0: 32 -> 2; KIND1: 16 -> 1)
    const unsigned short* gA = A + (size_t)(m0 + wid * 32 + sr) * 1024 + sc;
    const unsigned short* gB = Bt + (size_t)(n0 + wid * (BN / 4) + sr) * 1024 + sc;
    unsigned short* lA = a_s + wid * 1024;
    unsigned short* lB = b_s + wid * (BN / 4) * 32;

    floatx4 acc[NI][NJ];
    #pragma unroll
    for (int i = 0; i < NI; i++)
        #pragma unroll
        for (int j = 0; j < NJ; j++)
            acc[i][j] = floatx4{0.f, 0.f, 0.f, 0.f};

    for (int k0 = 0; k0 < 1024; k0 += 32) {
        __syncthreads();
        glds16(gA + k0, lA);
        glds16(gA + k0 + 16 * 1024, lA + 512);
        glds16(gB + k0, lB);
        if constexpr (KIND == 0) glds16(gB + k0 + 16 * 1024, lB + 512);
        __syncthreads();

        ABFrag af[NI], bf4[NJ];
        #pragma unroll
        for (int i = 0; i < NI; i++)
            af[i].q = *(const uint4*)(a_s + (wm + i * 16 + l15) * 32 + quad * 8);
        #pragma unroll
        for (int j = 0; j < NJ; j++)
            bf4[j].q = *(const uint4*)(b_s + (wn + j * 16 + l15) * 32 + quad * 8);
        #pragma unroll
        for (int i = 0; i < NI; i++)
            #pragma unroll
            for (int j = 0; j < NJ; j++)
                acc[i][j] = __builtin_amdgcn_mfma_f32_16x16x32_bf16(
                    af[i].v, bf4[j].v, acc[i][j], 0, 0, 0);
    }

    // ---- epilogue: C/D layout col=lane&15, row=quad*4+reg ----
    if constexpr (KIND == 1) {
        float* out = (float*)out0;
        #pragma unroll
        for (int j = 0; j < NJ; j++) {
            int gn = n0 + wn + j * 16 + l15;
            float bval = bias[gn];
            #pragma unroll
            for (int i = 0; i < NI; i++)
                #pragma unroll
                for (int r = 0; r < 4; r++) {
                    int gm = m0 + wm + i * 16 + quad * 4 + r;
                    out[(size_t)gm * 1024 + gn] = acc[i][j][r] + bval;
                }
        }
    } else {
        if (bz == 0) {
            // Q: linear [bh][s][64], pre-scaled by 0.125*log2(e) (softmax fold)
            const float SCQ = 0.125f * 1.44269504088896f;
            unsigned short* out = (unsigned short*)out0;
            #pragma unroll
            for (int j = 0; j < NJ; j++) {
                int gn = n0 + wn + j * 16 + l15;
                float bval = bias[gn];
                int h = gn >> 6, d = gn & 63;
                #pragma unroll
                for (int i = 0; i < NI; i++)
                    #pragma unroll
                    for (int r = 0; r < 4; r++) {
                        int gm = m0 + wm + i * 16 + quad * 4 + r;
                        int b = gm >> 11, s = gm & 2047;
                        out[(((size_t)(b * 16 + h) * 2048 + s) << 6) + d] =
                            f2bf((acc[i][j][r] + bval) * SCQ);
                    }
            }
        } else if (bz == 1) {
            // K: [bh][s][64] with 16B-granule XOR swizzle: granule ^= (s & 7)
            unsigned short* out = (unsigned short*)out1;
            #pragma unroll
            for (int j = 0; j < NJ; j++) {
                int gn = n0 + wn + j * 16 + l15;
                float bval = bias[gn];
                int h = gn >> 6, d = gn & 63;
                int dg = d >> 3, dl = d & 7;
                #pragma unroll
                for (int i = 0; i < NI; i++)
                    #pragma unroll
                    for (int r = 0; r < 4; r++) {
                        int gm = m0 + wm + i * 16 + quad * 4 + r;
                        int b = gm >> 11, s = gm & 2047;
                        int dphys = ((dg ^ (s & 7)) << 3) | dl;
                        out[(((size_t)(b * 16 + h) * 2048 + s) << 6) + dphys] =
                            f2bf(acc[i][j][r] + bval);
                    }
            }
        } else {
            // V: chunked [bh][chunk][d][64key]; key order permuted so phys granule
            // gp = s2*4+q holds logical keys {32s2+4q+0..3, 32s2+16+4q+0..3}
            // (= P^T C-layout order); 16B granules swizzled by ^(d&7).
            // R11: TWO-PASS over m-halves with t_s[128][72] (18.4KB, was
            // 34.8KB): pass mh stores waves wid>>1==mh (their wm = 64*mh);
            // reread uses chunk0+mh and src col-offset 0 (old: half*64).
            __shared__ unsigned short t_s[128][72];
            unsigned short* out = (unsigned short*)out2;
            const int n    = tid >> 1;           // t_s row = n-index in tile
            const int gph  = tid & 1;            // granule-pair half
            const int bh = (m0 >> 11) * 16 + ((n0 + n) >> 6);
            const int d  = (n0 + n) & 63;
            const int dmask  = d & 7;
            const int chunk0 = (m0 & 2047) >> 6;
            #pragma unroll
            for (int mh = 0; mh < 2; mh++) {
                if ((wid >> 1) == mh) {
                    #pragma unroll
                    for (int j = 0; j < NJ; j++) {
                        int nl = wn + j * 16 + l15;
                        float bval = bias[n0 + nl];
                        #pragma unroll
                        for (int i = 0; i < NI; i++)
                            #pragma unroll
                            for (int r = 0; r < 4; r++)
                                t_s[nl][i * 16 + quad * 4 + r] =
                                    f2bf(acc[i][j][r] + bval);
                    }
                }
                __syncthreads();
                {
                    unsigned short* dstb =
                        out + ((size_t)(bh * 32 + chunk0 + mh) * 64 + d) * 64;
                    const unsigned short* src = &t_s[n][0];
                    #pragma unroll
                    for (int g = 0; g < 4; g++) {
                        int gp = gph * 4 + g;
                        int u1 = 32 * (gp >> 2) + 4 * (gp & 3);
                        uint2 lo = *(const uint2*)(src + u1);
                        uint2 hi = *(const uint2*)(src + u1 + 16);
                        unsigned short* dq = dstb + ((gp ^ dmask) << 3);
                        *(uint2*)dq       = lo;
                        *(uint2*)(dq + 4) = hi;
                    }
                }
                __syncthreads();   // t_s reused by next pass
            }
        }
    }
}

// ---------------------------------------------------------------------------
// Flash attention, S^T form, offset-free streaming softmax (R9 config).
// 8 waves = 4 q-waves x 64 q (jq=0..3) x 2 key-halves; tile 256 q.
// grid (8,32) = 256 blocks = 1/CU. Each K/V LDS fragment feeds 4 MFMAs.
// ---------------------------------------------------------------------------
__launch_bounds__(512, 2)
__global__ void attn_kernel(const unsigned short* __restrict__ Q,
                            const unsigned short* __restrict__ K,
                            const unsigned short* __restrict__ Vt,
                            unsigned short* __restrict__ ctx)
{
    __shared__ unsigned short smem[2][2][2][4096];   // [buf][khalf][K/V][64*64]

    // ---- T1 XCD swizzle: grid (8,32), nwg=256, cpx=32 ----
    const int lin = blockIdx.x + (blockIdx.y << 3);
    const int swz = ((lin & 7) << 5) + (lin >> 3);
    const int qx  = swz & 7;           // q-tile (256 q each)
    const int bh  = swz >> 3;          // head

    const int tid  = threadIdx.x;
    const int wid  = tid >> 6;        // 0..7
    const int kh   = wid >> 2;        // key-half: 0 -> keys 0..1023, 1 -> 1024..2047
    const int wq   = wid & 3;         // q-subtile (64 q) within the 256-q tile
    const int lane = tid & 63;
    const int quad = lane >> 4;
    const int l15  = lane & 15;
    const int xr   = l15 & 7;

    const unsigned short* Qh = Q + (size_t)bh * (2048 * 64);
    const char* Kc = (const char*)(K  + (size_t)bh * (2048 * 64)) + (size_t)kh * (16 * 8192);
    const char* Vc = (const char*)(Vt + (size_t)bh * (2048 * 64)) + (size_t)kh * (16 * 8192);
    const int q0 = qx * 256 + wq * 64;

    // Q fragments (B-operand layout: lane holds Q[q=l15][k=quad*8+j])
    ABFrag qf[4][2];
    #pragma unroll
    for (int jq = 0; jq < 4; jq++)
        #pragma unroll
        for (int s = 0; s < 2; s++)
            qf[jq][s].q = *(const uint4*)(Qh + (size_t)(q0 + jq * 16 + l15) * 64
                                          + s * 32 + quad * 8);

    // swizzled LDS fragment column offsets (elements)
    int kcol[2];
    kcol[0] = ((quad    ) ^ xr) << 3;
    kcol[1] = ((quad + 4) ^ xr) << 3;   // also V phys granule s2*4+quad, s2=0/1

    floatx4 acc[4][4];
    #pragma unroll
    for (int i = 0; i < 4; i++)
        #pragma unroll
        for (int jq = 0; jq < 4; jq++)
            acc[i][jq] = floatx4{0.f, 0.f, 0.f, 0.f};
    float lrun[4] = {0.f, 0.f, 0.f, 0.f};

    // per key-half: 4 waves stage 16 KB (K 8 KB + V 8 KB) per chunk
    auto stage = [&](int c, int b) {
        const char* gk = Kc + (size_t)c * 8192 + wq * 2048 + lane * 16;
        char* lk = (char*)&smem[b][kh][0][0] + wq * 2048;
        glds16(gk,        lk);
        glds16(gk + 1024, lk + 1024);
        const char* gv = Vc + (size_t)c * 8192 + wq * 2048 + lane * 16;
        char* lv = (char*)&smem[b][kh][1][0] + wq * 2048;
        glds16(gv,        lv);
        glds16(gv + 1024, lv + 1024);
    };

    stage(0, 0);

    for (int c = 0; c < 16; ++c) {
        const int b = c & 1;
        __syncthreads();                 // drains glds for buf b; protects b^1 reuse
        if (c + 1 < 16) stage(c + 1, b ^ 1);

        const unsigned short* ks = &smem[b][kh][0][0];
        const unsigned short* vs = &smem[b][kh][1][0];

        // ---- S^T = K Q'^T: each K fragment pair feeds 4 jq MFMA pairs ----
        floatx4 st[4][4];
        #pragma unroll
        for (int kt = 0; kt < 4; kt++) {
            ABFrag k0, k1;
            const unsigned short* kr = ks + (kt * 16 + l15) * 64;
            k0.q = *(const uint4*)(kr + kcol[0]);
            k1.q = *(const uint4*)(kr + kcol[1]);
            #pragma unroll
            for (int jq = 0; jq < 4; jq++) {
                floatx4 t = floatx4{0.f, 0.f, 0.f, 0.f};
                t = __builtin_amdgcn_mfma_f32_16x16x32_bf16(k0.v, qf[jq][0].v, t, 0, 0, 0);
                t = __builtin_amdgcn_mfma_f32_16x16x32_bf16(k1.v, qf[jq][1].v, t, 0, 0, 0);
                st[kt][jq] = t;
            }
        }

        // ---- offset-free softmax: p = 2^s', accumulate per-lane l partials ----
        unsigned int pk[4][4][2];
        #pragma unroll
        for (int jq = 0; jq < 4; jq++) {
            float ls = 0.f;
            #pragma unroll
            for (int kt = 0; kt < 4; kt++) {
                #pragma unroll
                for (int t2 = 0; t2 < 2; t2++) {
                    float p0 = EXP2F(st[kt][jq][2 * t2 + 0]);
                    float p1 = EXP2F(st[kt][jq][2 * t2 + 1]);
                    ls += p0 + p1;
                    pk[kt][jq][t2] = cvtpk(p0, p1);
                }
            }
            lrun[jq] += ls;
        }

        // ---- O^T += V P^T: each V fragment feeds 4 jq MFMAs ----
        #pragma unroll
        for (int s2 = 0; s2 < 2; s2++) {
            ABFrag pf[4];
            #pragma unroll
            for (int jq = 0; jq < 4; jq++) {
                pf[jq].w[0] = pk[2 * s2 + 0][jq][0];
                pf[jq].w[1] = pk[2 * s2 + 0][jq][1];
                pf[jq].w[2] = pk[2 * s2 + 1][jq][0];
                pf[jq].w[3] = pk[2 * s2 + 1][jq][1];
            }
            #pragma unroll
            for (int i = 0; i < 4; i++) {
                ABFrag vf;
                vf.q = *(const uint4*)(vs + (i * 16 + l15) * 64 + kcol[s2]);
                #pragma unroll
                for (int jq = 0; jq < 4; jq++)
                    acc[i][jq] = __builtin_amdgcn_mfma_f32_16x16x32_bf16(
                        vf.v, pf[jq].v, acc[i][jq], 0, 0, 0);
            }
        }
    }

    // ---- cross-half combine (two passes; offset-free => plain adds) ----
    __syncthreads();                      // all waves done reading smem buffers
    float* sf = (float*)&smem[0][0][0][0];
    float* myp = sf + (size_t)(wq * 64 + lane) * 36;   // 144B stride
    // pass 0: acc[0..1][0..3] + lrun[0..1]
    if (kh) {
        #pragma unroll
        for (int i = 0; i < 2; i++)
            #pragma unroll
            for (int jq = 0; jq < 4; jq++)
                *(floatx4*)(myp + (i * 4 + jq) * 4) = acc[i][jq];
        myp[32] = lrun[0];
        myp[33] = lrun[1];
    }
    __syncthreads();
    if (!kh) {
        #pragma unroll
        for (int i = 0; i < 2; i++)
            #pragma unroll
            for (int jq = 0; jq < 4; jq++)
                acc[i][jq] += *(const floatx4*)(myp + (i * 4 + jq) * 4);
        lrun[0] += myp[32];
        lrun[1] += myp[33];
    }
    __syncthreads();
    // pass 1: acc[2..3][0..3] + lrun[2..3]
    if (kh) {
        #pragma unroll
        for (int i = 2; i < 4; i++)
            #pragma unroll
            for (int jq = 0; jq < 4; jq++)
                *(floatx4*)(myp + ((i - 2) * 4 + jq) * 4) = acc[i][jq];
        myp[32] = lrun[2];
        myp[33] = lrun[3];
    }
    __syncthreads();
    if (!kh) {
        #pragma unroll
        for (int i = 2; i < 4; i++)
            #pragma unroll
            for (int jq = 0; jq < 4; jq++)
                acc[i][jq] += *(const floatx4*)(myp + ((i - 2) * 4 + jq) * 4);
        lrun[2] += myp[32];
        lrun[3] += myp[33];

        // ---- epilogue: O^T[d][q] -> ctx[b, q, h*64+d], 4 d's per lane ----
        const int b_ = bh >> 4, h = bh & 15;
        #pragma unroll
        for (int jq = 0; jq < 4; jq++) {
            float s = lrun[jq];
            s += __shfl_xor(s, 16, 64);
            s += __shfl_xor(s, 32, 64);
            float inv = 1.0f / s;
            int q = q0 + jq * 16 + l15;
            size_t base = (size_t)(b_ * 2048 + q) * 1024 + h * 64;
            #pragma unroll
            for (int i = 0; i < 4; i++) {
                float v0 = acc[i][jq][0] * inv, v1 = acc[i][jq][1] * inv;
                float v2 = acc[i][jq][2] * inv, v3 = acc[i][jq][3] * inv;
                uint2 w2 = make_uint2(cvtpk(v0, v1), cvtpk(v2, v3));
                *(uint2*)(ctx + base + i * 16 + quad * 4) = w2;
            }
        }
    }
}

// ---------------------------------------------------------------------------
extern "C" void kernel_launch(void* const* d_in, const int* in_sizes, int n_in,
                              void* d_out, int out_size, void* d_ws, size_t ws_size,
                              hipStream_t stream)
{
    const float* x  = (const float*)d_in[0];
    const float* wq = (const float*)d_in[1];
    const float* bq = (const float*)d_in[2];
    const float* wk = (const float*)d_in[3];
    const float* bk = (const float*)d_in[4];
    const float* wv = (const float*)d_in[5];
    const float* bv = (const float*)d_in[6];
    const float* wo = (const float*)d_in[7];
    const float* bo = (const float*)d_in[8];

    const size_t NE = (size_t)4096 * 1024;
    unsigned short* xb  = (unsigned short*)d_ws;     // 8 MB
    unsigned short* wT  = xb  + NE;                  // 8 MB
    unsigned short* qb  = wT  + NE;                  // 8 MB
    unsigned short* kb  = qb  + NE;                  // 8 MB
    unsigned short* vtb = kb  + NE;                  // 8 MB
    unsigned short* ctx = vtb + NE;                  // 8 MB

    hipLaunchKernelGGL(convert_fused_kernel, dim3(6144), dim3(256), 0, stream,
                       x, wq, wk, wv, wo, xb, wT);
    hipLaunchKernelGGL((gemm_kernel<0>), dim3(8, 32, 3), dim3(256), 0, stream,
                       xb, wT, bq, bk, bv, (void*)qb, (void*)kb, (void*)vtb);
    hipLaunchKernelGGL(attn_kernel, dim3(8, 32), dim3(512), 0, stream, qb, kb, vtb, ctx);
    hipLaunchKernelGGL((gemm_kernel<1>), dim3(16, 32), dim3(256), 0, stream,
                       ctx, wT + 3 * NE / 4, bo, nullptr, nullptr, d_out, nullptr, nullptr);
}

// Round 14
// 179.509 us; speedup vs baseline: 1.0185x; 1.0185x over previous
//
#include <hip/hip_runtime.h>
#include <cstdint>
#include <cstddef>

// MultiHeadSelfAttention: B=2, S=2048, D=1024, H=16, Hd=64
// R13 = FULL REVERT to R9 (best verified: 180.1us, passed).
// R12's attn re-block (2 barrier domains/CU) FAILED correctness with a
// launch-varying error (2.2e-2 / 468) -- race not identified by audit;
// reverted per rigor discipline.
// Pipeline (4 dispatches):
//   0.  convert_fused: xb = bf16(x) AND wT = bf16(transpose(w))
//   1.  fused QKV GEMM, 128x128, grid (8,32,3), (256,2), one-pass V epilogue.
//   2.  flash attention: 8 waves = 4 q-waves x 64q (jq=0..3) x 2 key-halves,
//         tile 256q, grid (8,32)=256 blocks. Offset-free streaming softmax
//         (p=2^{s'}, scores O(+-5): no max subtraction). Each K/V LDS
//         fragment feeds 4 MFMAs. Two-pass cross-kh combine via LDS.
//   3.  O-proj GEMM -> fp32 d_out (64x64, grid (16,64), (256,2)).
//
// Measured history: R0 occup 18%; R1 8wx16q LDS-pipe 2x; R2 kh-split 48.4;
// R3 reg-batch spill; R4 setprio null; R6 cvtpk -4us + convert-fuse;
// R7 XCD swizzle (attn FETCH 71->14MB); R8 small-tile QKV regressed;
// R9 64q/wave attn 43.3us (this config); R10/R11 = noise (+-4us band);
// R12 phase-diversity attn = correctness FAIL.

typedef float floatx4 __attribute__((ext_vector_type(4)));
typedef __bf16 bf16x8 __attribute__((ext_vector_type(8)));
union ABFrag { bf16x8 v; uint4 q; unsigned short u[8]; unsigned int w[4]; };

__device__ __forceinline__ unsigned short f2bf(float f) {
    unsigned int u = __builtin_bit_cast(unsigned int, f);
    return (unsigned short)((u + 0x7FFFu + ((u >> 16) & 1u)) >> 16);  // RNE
}

// pack two floats to bf16x2 in ONE VALU op (RNE)
__device__ __forceinline__ unsigned int cvtpk(float lo, float hi) {
    unsigned int r;
    asm("v_cvt_pk_bf16_f32 %0, %1, %2" : "=v"(r) : "v"(lo), "v"(hi));
    return r;
}

#if __has_builtin(__builtin_amdgcn_exp2f)
#define EXP2F(x) __builtin_amdgcn_exp2f(x)
#else
#define EXP2F(x) exp2f(x)
#endif

// async global->LDS, 16B/lane; LDS dst = wave-uniform base + lane*16
__device__ __forceinline__ void glds16(const void* g, void* l) {
    __builtin_amdgcn_global_load_lds(
        (const __attribute__((address_space(1))) unsigned int*)(uintptr_t)g,
        (__attribute__((address_space(3))) unsigned int*)(unsigned int)(uintptr_t)l,
        16, 0, 0);
}

// ---------------------------------------------------------------------------
// Fused convert. Blocks [0,2048): x -> bf16. Blocks [2048,6144): w -> wT.
// ---------------------------------------------------------------------------
__global__ void convert_fused_kernel(const float* __restrict__ x,
                                     const float* __restrict__ w0,
                                     const float* __restrict__ w1,
                                     const float* __restrict__ w2,
                                     const float* __restrict__ w3,
                                     unsigned short* __restrict__ xb,
                                     unsigned short* __restrict__ wT) {
    const int tid = threadIdx.x;
    if (blockIdx.x < 2048) {
        int i = (blockIdx.x * 256 + tid) * 8;
        float4 a = *(const float4*)(x + i);
        float4 b = *(const float4*)(x + i + 4);
        union { unsigned short u[8]; uint4 q; } o;
        o.u[0] = f2bf(a.x); o.u[1] = f2bf(a.y); o.u[2] = f2bf(a.z); o.u[3] = f2bf(a.w);
        o.u[4] = f2bf(b.x); o.u[5] = f2bf(b.y); o.u[6] = f2bf(b.z); o.u[7] = f2bf(b.w);
        *(uint4*)(xb + i) = o.q;
        return;
    }
    __shared__ unsigned short t[32][40];
    const int wi = blockIdx.x - 2048;          // [0,4096)
    const int z  = wi >> 10;                   // weight matrix 0..3
    const int rem = wi & 1023;
    const int k0 = (rem >> 5) * 32, n0 = (rem & 31) * 32;
    const float* w = (z == 0) ? w0 : (z == 1) ? w1 : (z == 2) ? w2 : w3;
    unsigned short* dst = wT + (size_t)z * 1024 * 1024;
    {
        int ry = tid >> 3, cx = (tid & 7) * 4;
        float4 v = *(const float4*)(w + (size_t)(k0 + ry) * 1024 + n0 + cx);
        t[cx + 0][ry] = f2bf(v.x); t[cx + 1][ry] = f2bf(v.y);
        t[cx + 2][ry] = f2bf(v.z); t[cx + 3][ry] = f2bf(v.w);
    }
    __syncthreads();
    int n = tid >> 3, kc = (tid & 7) * 4;
    *(uint2*)(dst + (size_t)(n0 + n) * 1024 + k0 + kc) = *(const uint2*)&t[n][kc];
}

// ---------------------------------------------------------------------------
// m97-style GEMM (R9 config). KIND 0: fused QKV, 128x128, grid (8,32,3).
// KIND 1: O-proj, fp32 out, 64x64, grid (16,64).
// XCD swizzle: work id = (hwlin&7)*cpx + hwlin>>3 (bijective, nwg%8==0).
// ---------------------------------------------------------------------------
template<int KIND>
__launch_bounds__(256, 2)
__global__ void gemm_kernel(const unsigned short* __restrict__ A,
                            const unsigned short* __restrict__ wT,
                            const float* __restrict__ bias0,
                            const float* __restrict__ bias1,
                            const float* __restrict__ bias2,
                            void* __restrict__ out0,
                            void* __restrict__ out1,
                            void* __restrict__ out2)
{
    constexpr int BM = (KIND == 1) ? 64 : 128;
    constexpr int BN = (KIND == 1) ? 64 : 128;
    constexpr int NI = BM / 32;
    constexpr int NJ = BN / 32;

    __shared__ unsigned short a_s[BM * 32];
    __shared__ unsigned short b_s[BN * 32];

    // ---- T1 XCD swizzle ----
    int bx, by, bz;
    if constexpr (KIND == 0) {
        // grid (8,32,3), nwg=768, cpx=96; layout x + 8y + 256z (z-major/XCD)
        int lin = blockIdx.x + (blockIdx.y << 3) + (blockIdx.z << 8);
        int swz = (lin & 7) * 96 + (lin >> 3);
        bx = swz & 7;
        int rem = swz >> 3;            // y + 32z, [0,96)
        by = rem & 31;
        bz = rem >> 5;
    } else {
        // grid (16,64), nwg=1024, cpx=128
        int lin = blockIdx.x + (blockIdx.y << 4);
        int swz = ((lin & 7) << 7) + (lin >> 3);
        bx = swz & 15;
        by = swz >> 4;
        bz = 0;
    }

    const int tid  = threadIdx.x;
    const int wid  = tid >> 6;
    const int lane = tid & 63;
    const int quad = lane >> 4;
    const int l15  = lane & 15;
    const int wm   = (wid >> 1) * (BM / 2);
    const int wn   = (wid & 1) * (BN / 2);
    const int m0   = by * BM;
    const int n0   = bx * BN;

    const unsigned short* Bt = (KIND == 0) ? wT + (size_t)bz * (1024 * 1024) : wT;
    const float* bias = (KIND == 0)
        ? (bz == 0 ? bias0 : bz == 1 ? bias1 : bias2) : bias0;

    const int sr = lane >> 2;
    const int sc = (lane & 3) * 8;
    // staging rows/wave: BM/4 (KIND0: 32 -> 2 glds; KIND1: 16 -> 1 glds)
    const unsigned short* gA = A + (size_t)(m0 + wid * (BM / 4) + sr) * 1024 + sc;
    const unsigned short* gB = Bt + (size_t)(n0 + wid * (BN / 4) + sr) * 1024 + sc;
    unsigned short* lA = a_s + wid * (BM / 4) * 32;
    unsigned short* lB = b_s + wid * (BN / 4) * 32;

    floatx4 acc[NI][NJ];
    #pragma unroll
    for (int i = 0; i < NI; i++)
        #pragma unroll
        for (int j = 0; j < NJ; j++)
            acc[i][j] = floatx4{0.f, 0.f, 0.f, 0.f};

    for (int k0 = 0; k0 < 1024; k0 += 32) {
        __syncthreads();
        glds16(gA + k0, lA);
        if constexpr (KIND == 0) glds16(gA + k0 + 16 * 1024, lA + 512);
        glds16(gB + k0, lB);
        if constexpr (KIND == 0) glds16(gB + k0 + 16 * 1024, lB + 512);
        __syncthreads();

        ABFrag af[NI], bf4[NJ];
        #pragma unroll
        for (int i = 0; i < NI; i++)
            af[i].q = *(const uint4*)(a_s + (wm + i * 16 + l15) * 32 + quad * 8);
        #pragma unroll
        for (int j = 0; j < NJ; j++)
            bf4[j].q = *(const uint4*)(b_s + (wn + j * 16 + l15) * 32 + quad * 8);
        #pragma unroll
        for (int i = 0; i < NI; i++)
            #pragma unroll
            for (int j = 0; j < NJ; j++)
                acc[i][j] = __builtin_amdgcn_mfma_f32_16x16x32_bf16(
                    af[i].v, bf4[j].v, acc[i][j], 0, 0, 0);
    }

    // ---- epilogue: C/D layout col=lane&15, row=quad*4+reg ----
    if constexpr (KIND == 1) {
        float* out = (float*)out0;
        #pragma unroll
        for (int j = 0; j < NJ; j++) {
            int gn = n0 + wn + j * 16 + l15;
            float bval = bias[gn];
            #pragma unroll
            for (int i = 0; i < NI; i++)
                #pragma unroll
                for (int r = 0; r < 4; r++) {
                    int gm = m0 + wm + i * 16 + quad * 4 + r;
                    out[(size_t)gm * 1024 + gn] = acc[i][j][r] + bval;
                }
        }
    } else {
        if (bz == 0) {
            // Q: linear [bh][s][64], pre-scaled by 0.125*log2(e) (softmax fold)
            const float SCQ = 0.125f * 1.44269504088896f;
            unsigned short* out = (unsigned short*)out0;
            #pragma unroll
            for (int j = 0; j < NJ; j++) {
                int gn = n0 + wn + j * 16 + l15;
                float bval = bias[gn];
                int h = gn >> 6, d = gn & 63;
                #pragma unroll
                for (int i = 0; i < NI; i++)
                    #pragma unroll
                    for (int r = 0; r < 4; r++) {
                        int gm = m0 + wm + i * 16 + quad * 4 + r;
                        int b = gm >> 11, s = gm & 2047;
                        out[(((size_t)(b * 16 + h) * 2048 + s) << 6) + d] =
                            f2bf((acc[i][j][r] + bval) * SCQ);
                    }
            }
        } else if (bz == 1) {
            // K: [bh][s][64] with 16B-granule XOR swizzle: granule ^= (s & 7)
            unsigned short* out = (unsigned short*)out1;
            #pragma unroll
            for (int j = 0; j < NJ; j++) {
                int gn = n0 + wn + j * 16 + l15;
                float bval = bias[gn];
                int h = gn >> 6, d = gn & 63;
                int dg = d >> 3, dl = d & 7;
                #pragma unroll
                for (int i = 0; i < NI; i++)
                    #pragma unroll
                    for (int r = 0; r < 4; r++) {
                        int gm = m0 + wm + i * 16 + quad * 4 + r;
                        int b = gm >> 11, s = gm & 2047;
                        int dphys = ((dg ^ (s & 7)) << 3) | dl;
                        out[(((size_t)(b * 16 + h) * 2048 + s) << 6) + dphys] =
                            f2bf(acc[i][j][r] + bval);
                    }
            }
        } else {
            // V: chunked [bh][chunk][d][64key]; key order permuted so phys granule
            // gp = s2*4+q holds logical keys {32s2+4q+0..3, 32s2+16+4q+0..3}
            // (= P^T C-layout order); 16B granules swizzled by ^(d&7).
            __shared__ unsigned short t_s[128][136];
            #pragma unroll
            for (int j = 0; j < NJ; j++) {
                int nl = wn + j * 16 + l15;
                float bval = bias[n0 + nl];
                #pragma unroll
                for (int i = 0; i < NI; i++)
                    #pragma unroll
                    for (int r = 0; r < 4; r++)
                        t_s[nl][wm + i * 16 + quad * 4 + r] = f2bf(acc[i][j][r] + bval);
            }
            __syncthreads();
            unsigned short* out = (unsigned short*)out2;
            const int n  = tid >> 1, half = tid & 1;
            const int bh = (m0 >> 11) * 16 + ((n0 + n) >> 6);
            const int d  = (n0 + n) & 63;
            const int chunk = ((m0 & 2047) >> 6) + half;
            const int dmask = d & 7;
            unsigned short* dstb = out + ((size_t)(bh * 32 + chunk) * 64 + d) * 64;
            const unsigned short* src = &t_s[n][half * 64];
            #pragma unroll
            for (int gp = 0; gp < 8; gp++) {
                int u1 = 32 * (gp >> 2) + 4 * (gp & 3);
                uint2 lo = *(const uint2*)(src + u1);
                uint2 hi = *(const uint2*)(src + u1 + 16);
                unsigned short* dq = dstb + ((gp ^ dmask) << 3);
                *(uint2*)dq       = lo;
                *(uint2*)(dq + 4) = hi;
            }
        }
    }
}

// ---------------------------------------------------------------------------
// Flash attention, S^T form, offset-free streaming softmax (R9 config).
// 8 waves = 4 q-waves x 64 q (jq=0..3) x 2 key-halves; tile 256 q.
// grid (8,32) = 256 blocks. Each K/V LDS fragment feeds 4 MFMAs.
// Cross-half combine: two-pass LDS add (offset-free => plain sums).
// ---------------------------------------------------------------------------
__launch_bounds__(512, 2)
__global__ void attn_kernel(const unsigned short* __restrict__ Q,
                            const unsigned short* __restrict__ K,
                            const unsigned short* __restrict__ Vt,
                            unsigned short* __restrict__ ctx)
{
    __shared__ unsigned short smem[2][2][2][4096];   // [buf][khalf][K/V][64*64]

    // ---- T1 XCD swizzle: grid (8,32), nwg=256, cpx=32 ----
    const int lin = blockIdx.x + (blockIdx.y << 3);
    const int swz = ((lin & 7) << 5) + (lin >> 3);
    const int qx  = swz & 7;           // q-tile (256 q each)
    const int bh  = swz >> 3;          // head

    const int tid  = threadIdx.x;
    const int wid  = tid >> 6;        // 0..7
    const int kh   = wid >> 2;        // key-half: 0 -> keys 0..1023, 1 -> 1024..2047
    const int wq   = wid & 3;         // q-subtile (64 q) within the 256-q tile
    const int lane = tid & 63;
    const int quad = lane >> 4;
    const int l15  = lane & 15;
    const int xr   = l15 & 7;

    const unsigned short* Qh = Q + (size_t)bh * (2048 * 64);
    const char* Kc = (const char*)(K  + (size_t)bh * (2048 * 64)) + (size_t)kh * (16 * 8192);
    const char* Vc = (const char*)(Vt + (size_t)bh * (2048 * 64)) + (size_t)kh * (16 * 8192);
    const int q0 = qx * 256 + wq * 64;

    // Q fragments (B-operand layout: lane holds Q[q=l15][k=quad*8+j])
    ABFrag qf[4][2];
    #pragma unroll
    for (int jq = 0; jq < 4; jq++)
        #pragma unroll
        for (int s = 0; s < 2; s++)
            qf[jq][s].q = *(const uint4*)(Qh + (size_t)(q0 + jq * 16 + l15) * 64
                                          + s * 32 + quad * 8);

    // swizzled LDS fragment column offsets (elements)
    int kcol[2];
    kcol[0] = ((quad    ) ^ xr) << 3;
    kcol[1] = ((quad + 4) ^ xr) << 3;   // also V phys granule s2*4+quad, s2=0/1

    floatx4 acc[4][4];
    #pragma unroll
    for (int i = 0; i < 4; i++)
        #pragma unroll
        for (int jq = 0; jq < 4; jq++)
            acc[i][jq] = floatx4{0.f, 0.f, 0.f, 0.f};
    float lrun[4] = {0.f, 0.f, 0.f, 0.f};

    // per key-half: 4 waves stage 16 KB (K 8 KB + V 8 KB) per chunk
    auto stage = [&](int c, int b) {
        const char* gk = Kc + (size_t)c * 8192 + wq * 2048 + lane * 16;
        char* lk = (char*)&smem[b][kh][0][0] + wq * 2048;
        glds16(gk,        lk);
        glds16(gk + 1024, lk + 1024);
        const char* gv = Vc + (size_t)c * 8192 + wq * 2048 + lane * 16;
        char* lv = (char*)&smem[b][kh][1][0] + wq * 2048;
        glds16(gv,        lv);
        glds16(gv + 1024, lv + 1024);
    };

    stage(0, 0);

    for (int c = 0; c < 16; ++c) {
        const int b = c & 1;
        __syncthreads();                 // drains glds for buf b; protects b^1 reuse
        if (c + 1 < 16) stage(c + 1, b ^ 1);

        const unsigned short* ks = &smem[b][kh][0][0];
        const unsigned short* vs = &smem[b][kh][1][0];

        // ---- S^T = K Q'^T: each K fragment pair feeds 4 jq MFMA pairs ----
        floatx4 st[4][4];
        #pragma unroll
        for (int kt = 0; kt < 4; kt++) {
            ABFrag k0, k1;
            const unsigned short* kr = ks + (kt * 16 + l15) * 64;
            k0.q = *(const uint4*)(kr + kcol[0]);
            k1.q = *(const uint4*)(kr + kcol[1]);
            #pragma unroll
            for (int jq = 0; jq < 4; jq++) {
                floatx4 t = floatx4{0.f, 0.f, 0.f, 0.f};
                t = __builtin_amdgcn_mfma_f32_16x16x32_bf16(k0.v, qf[jq][0].v, t, 0, 0, 0);
                t = __builtin_amdgcn_mfma_f32_16x16x32_bf16(k1.v, qf[jq][1].v, t, 0, 0, 0);
                st[kt][jq] = t;
            }
        }

        // ---- offset-free softmax: p = 2^s', accumulate per-lane l partials ----
        unsigned int pk[4][4][2];
        #pragma unroll
        for (int jq = 0; jq < 4; jq++) {
            float ls = 0.f;
            #pragma unroll
            for (int kt = 0; kt < 4; kt++) {
                #pragma unroll
                for (int t2 = 0; t2 < 2; t2++) {
                    float p0 = EXP2F(st[kt][jq][2 * t2 + 0]);
                    float p1 = EXP2F(st[kt][jq][2 * t2 + 1]);
                    ls += p0 + p1;
                    pk[kt][jq][t2] = cvtpk(p0, p1);
                }
            }
            lrun[jq] += ls;
        }

        // ---- O^T += V P^T: each V fragment feeds 4 jq MFMAs ----
        #pragma unroll
        for (int s2 = 0; s2 < 2; s2++) {
            ABFrag pf[4];
            #pragma unroll
            for (int jq = 0; jq < 4; jq++) {
                pf[jq].w[0] = pk[2 * s2 + 0][jq][0];
                pf[jq].w[1] = pk[2 * s2 + 0][jq][1];
                pf[jq].w[2] = pk[2 * s2 + 1][jq][0];
                pf[jq].w[3] = pk[2 * s2 + 1][jq][1];
            }
            #pragma unroll
            for (int i = 0; i < 4; i++) {
                ABFrag vf;
                vf.q = *(const uint4*)(vs + (i * 16 + l15) * 64 + kcol[s2]);
                #pragma unroll
                for (int jq = 0; jq < 4; jq++)
                    acc[i][jq] = __builtin_amdgcn_mfma_f32_16x16x32_bf16(
                        vf.v, pf[jq].v, acc[i][jq], 0, 0, 0);
            }
        }
    }

    // ---- cross-half combine (two passes; offset-free => plain adds) ----
    __syncthreads();                      // all waves done reading smem buffers
    float* sf = (float*)&smem[0][0][0][0];
    float* myp = sf + (size_t)(wq * 64 + lane) * 36;   // 144B stride
    // pass 0: acc[0..1][0..3] + lrun[0..1]
    if (kh) {
        #pragma unroll
        for (int i = 0; i < 2; i++)
            #pragma unroll
            for (int jq = 0; jq < 4; jq++)
                *(floatx4*)(myp + (i * 4 + jq) * 4) = acc[i][jq];
        myp[32] = lrun[0];
        myp[33] = lrun[1];
    }
    __syncthreads();
    if (!kh) {
        #pragma unroll
        for (int i = 0; i < 2; i++)
            #pragma unroll
            for (int jq = 0; jq < 4; jq++)
                acc[i][jq] += *(const floatx4*)(myp + (i * 4 + jq) * 4);
        lrun[0] += myp[32];
        lrun[1] += myp[33];
    }
    __syncthreads();
    // pass 1: acc[2..3][0..3] + lrun[2..3]
    if (kh) {
        #pragma unroll
        for (int i = 2; i < 4; i++)
            #pragma unroll
            for (int jq = 0; jq < 4; jq++)
                *(floatx4*)(myp + ((i - 2) * 4 + jq) * 4) = acc[i][jq];
        myp[32] = lrun[2];
        myp[33] = lrun[3];
    }
    __syncthreads();
    if (!kh) {
        #pragma unroll
        for (int i = 2; i < 4; i++)
            #pragma unroll
            for (int jq = 0; jq < 4; jq++)
                acc[i][jq] += *(const floatx4*)(myp + ((i - 2) * 4 + jq) * 4);
        lrun[2] += myp[32];
        lrun[3] += myp[33];

        // ---- epilogue: O^T[d][q] -> ctx[b, q, h*64+d], 4 d's per lane ----
        const int b_ = bh >> 4, h = bh & 15;
        #pragma unroll
        for (int jq = 0; jq < 4; jq++) {
            float s = lrun[jq];
            s += __shfl_xor(s, 16, 64);
            s += __shfl_xor(s, 32, 64);
            float inv = 1.0f / s;
            int q = q0 + jq * 16 + l15;
            size_t base = (size_t)(b_ * 2048 + q) * 1024 + h * 64;
            #pragma unroll
            for (int i = 0; i < 4; i++) {
                float v0 = acc[i][jq][0] * inv, v1 = acc[i][jq][1] * inv;
                float v2 = acc[i][jq][2] * inv, v3 = acc[i][jq][3] * inv;
                uint2 w2 = make_uint2(cvtpk(v0, v1), cvtpk(v2, v3));
                *(uint2*)(ctx + base + i * 16 + quad * 4) = w2;
            }
        }
    }
}

// ---------------------------------------------------------------------------
extern "C" void kernel_launch(void* const* d_in, const int* in_sizes, int n_in,
                              void* d_out, int out_size, void* d_ws, size_t ws_size,
                              hipStream_t stream)
{
    const float* x  = (const float*)d_in[0];
    const float* wq = (const float*)d_in[1];
    const float* bq = (const float*)d_in[2];
    const float* wk = (const float*)d_in[3];
    const float* bk = (const float*)d_in[4];
    const float* wv = (const float*)d_in[5];
    const float* bv = (const float*)d_in[6];
    const float* wo = (const float*)d_in[7];
    const float* bo = (const float*)d_in[8];

    const size_t NE = (size_t)4096 * 1024;
    unsigned short* xb  = (unsigned short*)d_ws;     // 8 MB
    unsigned short* wT  = xb  + NE;                  // 8 MB
    unsigned short* qb  = wT  + NE;                  // 8 MB
    unsigned short* kb  = qb  + NE;                  // 8 MB
    unsigned short* vtb = kb  + NE;                  // 8 MB
    unsigned short* ctx = vtb + NE;                  // 8 MB

    hipLaunchKernelGGL(convert_fused_kernel, dim3(6144), dim3(256), 0, stream,
                       x, wq, wk, wv, wo, xb, wT);
    hipLaunchKernelGGL((gemm_kernel<0>), dim3(8, 32, 3), dim3(256), 0, stream,
                       xb, wT, bq, bk, bv, (void*)qb, (void*)kb, (void*)vtb);
    hipLaunchKernelGGL(attn_kernel, dim3(8, 32), dim3(512), 0, stream, qb, kb, vtb, ctx);
    hipLaunchKernelGGL((gemm_kernel<1>), dim3(16, 64), dim3(256), 0, stream,
                       ctx, wT + 3 * NE / 4, bo, nullptr, nullptr, d_out, nullptr, nullptr);
}